// Round 6
// baseline (303.066 us; speedup 1.0000x reference)
//
#include <hip/hip_runtime.h>
#include <hip/hip_bf16.h>
#include <stdint.h>

typedef unsigned short u16;
typedef unsigned int u32;
typedef __attribute__((ext_vector_type(8))) short short8;
typedef __attribute__((ext_vector_type(4))) float float4v;

#define CH 128
#define OO 128
#define KD 1152      // 9*128

__device__ __forceinline__ u16 f2bf(float v) {
    __hip_bfloat16 h = __float2bfloat16(v);
    return *reinterpret_cast<u16*>(&h);
}
__device__ __forceinline__ float bf_lo(u32 u) { u32 t = u << 16;         return __builtin_bit_cast(float, t); }
__device__ __forceinline__ float bf_hi(u32 u) { u32 t = u & 0xffff0000u; return __builtin_bit_cast(float, t); }
__device__ __forceinline__ u32 pack_bf16(float lo, float hi) {
    u32 ul = __builtin_bit_cast(u32, lo);
    u32 uh = __builtin_bit_cast(u32, hi);
    return ((ul + 0x8000u) >> 16) | ((uh + 0x8000u) & 0xffff0000u);
}

// ---------------- prep: transpose (bid<512) | offset conv (512..1023) | w-swizzle (1024..1095) ----
__global__ __launch_bounds__(256) void prep_kernel(const float* __restrict__ x,
                                                   const float* __restrict__ w_off,
                                                   const float* __restrict__ w_main,
                                                   __hip_bfloat16* __restrict__ xt,
                                                   float* __restrict__ partial,
                                                   u16* __restrict__ WbSwz) {
    __shared__ float st[64][65];
    int bid = blockIdx.x;
    int tid = threadIdx.x;
    if (bid < 512) {
        // transpose x (B,C,H,W) f32 -> xt (B,H,W,C) bf16
        int b = bid >> 6;
        int h = bid & 63;
        const float* xb = x + ((size_t)b * CH) * 4096 + (size_t)h * 64;
        __hip_bfloat16* xo = xt + ((size_t)bid << 6) * CH;
        for (int cc0 = 0; cc0 < 128; cc0 += 64) {
            #pragma unroll
            for (int step = 0; step < 16; ++step) {
                int cl = (tid >> 6) + step * 4;
                int w = tid & 63;
                st[cl][w] = xb[(size_t)(cc0 + cl) * 4096 + w];
            }
            __syncthreads();
            #pragma unroll
            for (int step = 0; step < 16; ++step) {
                int w = (tid >> 6) + step * 4;
                int cl = tid & 63;
                xo[(size_t)w * CH + cc0 + cl] = __float2bfloat16(st[cl][w]);
            }
            __syncthreads();
        }
    } else if (bid < 1024) {
        // offset conv: only the 6 needed channels, 4-way c-split
        int mb = (bid - 512) & 127;
        int chunk = (bid - 512) >> 7;
        int m = mb * 256 + tid;
        int b = m >> 12;
        int hw = m & 4095;
        int h = hw >> 6;
        int w = hw & 63;
        float acc[6] = {0.f, 0.f, 0.f, 0.f, 0.f, 0.f};
        int c0 = chunk * 32;
        for (int c = c0; c < c0 + 32; ++c) {
            const float* xc = x + ((size_t)(b * CH + c) << 12);
            float xv[9];
            #pragma unroll
            for (int dy = 0; dy < 3; ++dy) {
                int yy = h + dy - 1;
                bool vy = (unsigned)yy < 64u;
                #pragma unroll
                for (int dx = 0; dx < 3; ++dx) {
                    int xx = w + dx - 1;
                    bool vv = vy && ((unsigned)xx < 64u);
                    xv[dy * 3 + dx] = vv ? xc[yy * 64 + xx] : 0.f;
                }
            }
            const float* wbp = w_off + (size_t)c * 9;
            #pragma unroll
            for (int s = 0; s < 6; ++s) {
                int chn = (s < 3) ? s * 6 : (s - 3) * 2 + 1;
                const float* wp = wbp + (size_t)chn * (CH * 9);
                float a = acc[s];
                #pragma unroll
                for (int t = 0; t < 9; ++t) a = fmaf(xv[t], wp[t], a);
                acc[s] = a;
            }
        }
        float* po = partial + ((size_t)(chunk << 15) + m) * 6;
        #pragma unroll
        for (int s = 0; s < 6; ++s) po[s] = acc[s];
    } else {
        // w_main (O,C,3,3) f32 -> WbSwz: per (kc,t,lane) an 8-u16 A-fragment.
        // unit = kc*512 + t*64 + lane; o = t*16+(lane&15); k = kc*32+(lane>>4)*8+j
        int unit = (bid - 1024) * 256 + tid;      // 0..18431
        int lane6 = unit & 63;
        int t = (unit >> 6) & 7;
        int kc = unit >> 9;
        int o = t * 16 + (lane6 & 15);
        int q8 = (lane6 >> 4) * 8;
        int tap = kc >> 2;
        int cb = (kc & 3) * 32 + q8;
        u16 v8[8];
        #pragma unroll
        for (int j = 0; j < 8; ++j)
            v8[j] = f2bf(w_main[(size_t)o * KD + (cb + j) * 9 + tap]);
        *(uint4*)(WbSwz + (size_t)unit * 8) = *(const uint4*)v8;
    }
}

// ---------------- fused deformable-sample + GEMM v4 ----------------
// 2 waves/block, 16 pixels/block, K-split across waves (wave0: taps 0-3 + tap4 cc0-1,
// wave1: taps 5-8 + tap4 cc2-3). Barrier-free K-loop: B sampled into registers,
// A direct from L2-resident swizzled WbSwz. XCD swizzle: img = blockIdx&7.
// One LDS reduction (8 KB) at the end.
__global__ __launch_bounds__(128, 4) void fused_gemm_kernel(const __hip_bfloat16* __restrict__ xt,
                                                            const float* __restrict__ partial,
                                                            const float* __restrict__ b_off,
                                                            const u16* __restrict__ WbSwz,
                                                            const float* __restrict__ b_main,
                                                            float* __restrict__ out) {
    __shared__ float4v red[2][4][64];             // 8 KB

    int tid = threadIdx.x;
    int wave = tid >> 6;
    int lane = tid & 63;
    int col = lane & 15;                          // pixel-in-tile = MFMA col
    int q8 = (lane >> 4) * 8;                     // k-subgroup
    int img = blockIdx.x & 7;                     // XCD-aligned image
    int tile = blockIdx.x >> 3;                   // 0..255
    int pb = img * 4096 + tile * 16;
    int m = pb + col;                             // this lane's pixel
    int h = (m & 4095) >> 6;
    int w = m & 63;

    // ---- per-lane preamble: offsets -> sample coords ----
    float o6[6];
    #pragma unroll
    for (int s = 0; s < 6; ++s) {
        int chn = (s < 3) ? s * 6 : (s - 3) * 2 + 1;
        float v = b_off[chn];
        #pragma unroll
        for (int q = 0; q < 4; ++q) v += partial[((size_t)(q << 15) + m) * 6 + s];
        o6[s] = v;
    }
    float ox0 = o6[0], ox1 = ox0 + o6[1], ox2 = ox1 + o6[2];
    float oy0 = o6[3], oy1 = oy0 + o6[4], oy2 = oy1 + o6[5];
    const float step = 2.0f / 63.0f;
    float bxn = -1.0f + w * step;
    float byn = -1.0f + h * step;
    float gx0 = fmaf(bxn + ox0, 32.0f, 31.5f);
    float gx1 = fmaf(bxn + ox1, 32.0f, 31.5f);
    float gx2 = fmaf(bxn + ox2, 32.0f, 31.5f);
    float gy0 = fmaf(byn + oy0, 32.0f, 31.5f);
    float gy1 = fmaf(byn + oy1, 32.0f, 31.5f);
    float gy2 = fmaf(byn + oy2, 32.0f, 31.5f);

    const u32* xb = (const u32*)(xt + (((size_t)img << 12) * CH));   // bf16 pairs

    float4v acc[8];
    #pragma unroll
    for (int t = 0; t < 8; ++t) acc[t] = (float4v){0.f, 0.f, 0.f, 0.f};

    // process taps [t0, t0+ntap) with cc range [cc0, cc0+ncc)
    auto process_tap = [&](int tap, int ccb, int ncc) {
        float gxi = (tap >= 6) ? gx2 : ((tap >= 3) ? gx1 : gx0);   // i = tap/3
        int jm = tap - ((tap >= 6) ? 6 : ((tap >= 3) ? 3 : 0));    // j = tap%3
        float gyj = (jm == 2) ? gy2 : ((jm == 1) ? gy1 : gy0);
        float x0f = floorf(gxi), y0f = floorf(gyj);
        float wx = gxi - x0f, wy = gyj - y0f;
        int ix0 = (int)x0f, iy0 = (int)y0f;
        int ix1 = ix0 + 1, iy1 = iy0 + 1;
        float fx0 = ((unsigned)ix0 < 64u) ? 1.f : 0.f;
        float fx1 = ((unsigned)ix1 < 64u) ? 1.f : 0.f;
        float fy0 = ((unsigned)iy0 < 64u) ? 1.f : 0.f;
        float fy1 = ((unsigned)iy1 < 64u) ? 1.f : 0.f;
        float w00 = (1.f - wy) * (1.f - wx) * fy0 * fx0;
        float w01 = (1.f - wy) * wx * fy0 * fx1;
        float w10 = wy * (1.f - wx) * fy1 * fx0;
        float w11 = wy * wx * fy1 * fx1;
        int cx0 = min(max(ix0, 0), 63), cx1 = min(max(ix1, 0), 63);
        int cy0 = min(max(iy0, 0), 63), cy1 = min(max(iy1, 0), 63);
        int r00 = ((cy0 * 64 + cx0) * CH + q8) >> 1;   // u32 index
        int r01 = ((cy0 * 64 + cx1) * CH + q8) >> 1;
        int r10 = ((cy1 * 64 + cx0) * CH + q8) >> 1;
        int r11 = ((cy1 * 64 + cx1) * CH + q8) >> 1;

        #pragma unroll 4
        for (int q = 0; q < ncc; ++q) {
            int cc = ccb + q;
            int co = cc * 16;                     // u32 offset: 32 channels
            uint4 u00 = *(const uint4*)(xb + r00 + co);
            uint4 u01 = *(const uint4*)(xb + r01 + co);
            uint4 u10 = *(const uint4*)(xb + r10 + co);
            uint4 u11 = *(const uint4*)(xb + r11 + co);
            const u32* p00 = (const u32*)&u00;
            const u32* p01 = (const u32*)&u01;
            const u32* p10 = (const u32*)&u10;
            const u32* p11 = (const u32*)&u11;
            u32 bp[4];
            #pragma unroll
            for (int qq = 0; qq < 4; ++qq) {
                float lo = w00 * bf_lo(p00[qq]);
                lo = fmaf(w01, bf_lo(p01[qq]), lo);
                lo = fmaf(w10, bf_lo(p10[qq]), lo);
                lo = fmaf(w11, bf_lo(p11[qq]), lo);
                float hi = w00 * bf_hi(p00[qq]);
                hi = fmaf(w01, bf_hi(p01[qq]), hi);
                hi = fmaf(w10, bf_hi(p10[qq]), hi);
                hi = fmaf(w11, bf_hi(p11[qq]), hi);
                bp[qq] = pack_bf16(lo, hi);
            }
            short8 bfrag = *(const short8*)bp;
            const u16* Ap = WbSwz + ((size_t)((tap * 4 + cc) * 512 + lane) * 8);
            #pragma unroll
            for (int t = 0; t < 8; ++t) {
                short8 af = *(const short8*)(Ap + (size_t)t * 512);
                acc[t] = __builtin_amdgcn_mfma_f32_16x16x32_bf16(af, bfrag, acc[t], 0, 0, 0);
            }
        }
    };

    int t0 = wave ? 5 : 0;
    for (int tt = 0; tt < 4; ++tt) process_tap(t0 + tt, 0, 4);
    process_tap(4, wave * 2, 2);                  // split tap 4 between the waves

    // ---- cross-wave reduction: each wave donates the half it does NOT finalize ----
    #pragma unroll
    for (int s = 0; s < 4; ++s)
        red[wave][s][lane] = acc[wave ? s : 4 + s];
    __syncthreads();
    #pragma unroll
    for (int s = 0; s < 4; ++s) {
        if (wave == 0) acc[s] += red[1][s][lane];
        else           acc[4 + s] += red[0][s][lane];
    }

    // ---- epilogue: wave0 stores o 0..63 (t=0..3), wave1 stores o 64..127 (t=4..7) ----
    int quad4 = (lane >> 4) * 4;
    int rem = m & 4095;
    #pragma unroll
    for (int s = 0; s < 4; ++s) {
        int t = wave * 4 + s;
        int ob = t * 16 + quad4;
        float4 bm = *(const float4*)(b_main + ob);
        float* op = out + (((size_t)(img * OO + ob)) << 12) + rem;
        op[0] = acc[t][0] + bm.x;
        op[4096] = acc[t][1] + bm.y;
        op[8192] = acc[t][2] + bm.z;
        op[12288] = acc[t][3] + bm.w;
    }
}

extern "C" void kernel_launch(void* const* d_in, const int* in_sizes, int n_in,
                              void* d_out, int out_size, void* d_ws, size_t ws_size,
                              hipStream_t stream) {
    const float* x      = (const float*)d_in[0];
    const float* w_off  = (const float*)d_in[1];
    const float* b_off  = (const float*)d_in[2];
    const float* w_main = (const float*)d_in[3];
    const float* b_main = (const float*)d_in[4];
    float* out = (float*)d_out;

    char* ws = (char*)d_ws;
    __hip_bfloat16* xt = (__hip_bfloat16*)ws;                         // 8 MB
    float* partial = (float*)(ws + 8388608);                          // 3 MB
    u16* WbSwz = (u16*)(ws + 8388608 + 3145728);                      // 288 KB

    prep_kernel<<<1096, 256, 0, stream>>>(x, w_off, w_main, xt, partial, WbSwz);
    fused_gemm_kernel<<<2048, 128, 0, stream>>>(xt, partial, b_off, WbSwz, b_main, out);
}

// Round 7
// 233.716 us; speedup vs baseline: 1.2967x; 1.2967x over previous
//
#include <hip/hip_runtime.h>
#include <hip/hip_bf16.h>
#include <stdint.h>

typedef unsigned short u16;
typedef unsigned int u32;
typedef __attribute__((ext_vector_type(8))) short short8;
typedef __attribute__((ext_vector_type(4))) float float4v;

#define CH 128
#define OO 128
#define KD 1152      // 9*128

__device__ __forceinline__ u16 f2bf(float v) {
    __hip_bfloat16 h = __float2bfloat16(v);
    return *reinterpret_cast<u16*>(&h);
}
__device__ __forceinline__ float bf_lo(u32 u) { u32 t = u << 16;         return __builtin_bit_cast(float, t); }
__device__ __forceinline__ float bf_hi(u32 u) { u32 t = u & 0xffff0000u; return __builtin_bit_cast(float, t); }
__device__ __forceinline__ u32 pack_bf16(float lo, float hi) {
    u32 ul = __builtin_bit_cast(u32, lo);
    u32 uh = __builtin_bit_cast(u32, hi);
    return ((ul + 0x8000u) >> 16) | ((uh + 0x8000u) & 0xffff0000u);
}

// ---------------- prep: transpose (bid<512) | offset conv (512..1023) | w-swizzle (1024..1095) ----
__global__ __launch_bounds__(256) void prep_kernel(const float* __restrict__ x,
                                                   const float* __restrict__ w_off,
                                                   const float* __restrict__ w_main,
                                                   __hip_bfloat16* __restrict__ xt,
                                                   float* __restrict__ partial,
                                                   u16* __restrict__ WbSwz) {
    __shared__ float st[64][65];
    int bid = blockIdx.x;
    int tid = threadIdx.x;
    if (bid < 512) {
        // transpose x (B,C,H,W) f32 -> xt (B,H,W,C) bf16
        int b = bid >> 6;
        int h = bid & 63;
        const float* xb = x + ((size_t)b * CH) * 4096 + (size_t)h * 64;
        __hip_bfloat16* xo = xt + ((size_t)bid << 6) * CH;
        for (int cc0 = 0; cc0 < 128; cc0 += 64) {
            #pragma unroll
            for (int step = 0; step < 16; ++step) {
                int cl = (tid >> 6) + step * 4;
                int w = tid & 63;
                st[cl][w] = xb[(size_t)(cc0 + cl) * 4096 + w];
            }
            __syncthreads();
            #pragma unroll
            for (int step = 0; step < 16; ++step) {
                int w = (tid >> 6) + step * 4;
                int cl = tid & 63;
                xo[(size_t)w * CH + cc0 + cl] = __float2bfloat16(st[cl][w]);
            }
            __syncthreads();
        }
    } else if (bid < 1024) {
        // offset conv: only the 6 needed channels, 4-way c-split
        int mb = (bid - 512) & 127;
        int chunk = (bid - 512) >> 7;
        int m = mb * 256 + tid;
        int b = m >> 12;
        int hw = m & 4095;
        int h = hw >> 6;
        int w = hw & 63;
        float acc[6] = {0.f, 0.f, 0.f, 0.f, 0.f, 0.f};
        int c0 = chunk * 32;
        for (int c = c0; c < c0 + 32; ++c) {
            const float* xc = x + ((size_t)(b * CH + c) << 12);
            float xv[9];
            #pragma unroll
            for (int dy = 0; dy < 3; ++dy) {
                int yy = h + dy - 1;
                bool vy = (unsigned)yy < 64u;
                #pragma unroll
                for (int dx = 0; dx < 3; ++dx) {
                    int xx = w + dx - 1;
                    bool vv = vy && ((unsigned)xx < 64u);
                    xv[dy * 3 + dx] = vv ? xc[yy * 64 + xx] : 0.f;
                }
            }
            const float* wbp = w_off + (size_t)c * 9;
            #pragma unroll
            for (int s = 0; s < 6; ++s) {
                int chn = (s < 3) ? s * 6 : (s - 3) * 2 + 1;
                const float* wp = wbp + (size_t)chn * (CH * 9);
                float a = acc[s];
                #pragma unroll
                for (int t = 0; t < 9; ++t) a = fmaf(xv[t], wp[t], a);
                acc[s] = a;
            }
        }
        float* po = partial + ((size_t)(chunk << 15) + m) * 6;
        #pragma unroll
        for (int s = 0; s < 6; ++s) po[s] = acc[s];
    } else {
        // w_main (O,C,3,3) f32 -> WbSwz: per (kc,t,lane) an 8-u16 A-fragment.
        // unit = kc*512 + t*64 + lane; o = t*16+(lane&15); k = kc*32+(lane>>4)*8+j
        int unit = (bid - 1024) * 256 + tid;      // 0..18431
        int lane6 = unit & 63;
        int t = (unit >> 6) & 7;
        int kc = unit >> 9;
        int o = t * 16 + (lane6 & 15);
        int q8 = (lane6 >> 4) * 8;
        int tap = kc >> 2;
        int cb = (kc & 3) * 32 + q8;
        u16 v8[8];
        #pragma unroll
        for (int j = 0; j < 8; ++j)
            v8[j] = f2bf(w_main[(size_t)o * KD + (cb + j) * 9 + tap]);
        *(uint4*)(WbSwz + (size_t)unit * 8) = *(const uint4*)v8;
    }
}

// ---------------- fused deformable-sample + GEMM v5 ----------------
// Same as v4 but WITHOUT dynamic register-array indexing (v4 spilled acc[] to
// scratch: 618 MB WRITE_SIZE). All acc[] indices are compile-time constants
// inside wave-uniform branches.
__global__ __launch_bounds__(128, 4) void fused_gemm_kernel(const __hip_bfloat16* __restrict__ xt,
                                                            const float* __restrict__ partial,
                                                            const float* __restrict__ b_off,
                                                            const u16* __restrict__ WbSwz,
                                                            const float* __restrict__ b_main,
                                                            float* __restrict__ out) {
    __shared__ float4v red[2][4][64];             // 8 KB

    int tid = threadIdx.x;
    int wave = tid >> 6;
    int lane = tid & 63;
    int col = lane & 15;                          // pixel-in-tile = MFMA col
    int q8 = (lane >> 4) * 8;                     // k-subgroup
    int img = blockIdx.x & 7;                     // XCD-aligned image
    int tile = blockIdx.x >> 3;                   // 0..255
    int pb = img * 4096 + tile * 16;
    int m = pb + col;                             // this lane's pixel
    int h = (m & 4095) >> 6;
    int w = m & 63;

    // ---- per-lane preamble: offsets -> sample coords ----
    float o6[6];
    #pragma unroll
    for (int s = 0; s < 6; ++s) {
        int chn = (s < 3) ? s * 6 : (s - 3) * 2 + 1;
        float v = b_off[chn];
        #pragma unroll
        for (int q = 0; q < 4; ++q) v += partial[((size_t)(q << 15) + m) * 6 + s];
        o6[s] = v;
    }
    float ox0 = o6[0], ox1 = ox0 + o6[1], ox2 = ox1 + o6[2];
    float oy0 = o6[3], oy1 = oy0 + o6[4], oy2 = oy1 + o6[5];
    const float step = 2.0f / 63.0f;
    float bxn = -1.0f + w * step;
    float byn = -1.0f + h * step;
    float gx0 = fmaf(bxn + ox0, 32.0f, 31.5f);
    float gx1 = fmaf(bxn + ox1, 32.0f, 31.5f);
    float gx2 = fmaf(bxn + ox2, 32.0f, 31.5f);
    float gy0 = fmaf(byn + oy0, 32.0f, 31.5f);
    float gy1 = fmaf(byn + oy1, 32.0f, 31.5f);
    float gy2 = fmaf(byn + oy2, 32.0f, 31.5f);

    const u32* xb = (const u32*)(xt + (((size_t)img << 12) * CH));   // bf16 pairs

    float4v acc[8];
    #pragma unroll
    for (int t = 0; t < 8; ++t) acc[t] = (float4v){0.f, 0.f, 0.f, 0.f};

    // process one tap over cc range [ccb, ccb+ncc); acc indices all constant
    auto process_tap = [&](int tap, int ccb, int ncc) {
        float gxi = (tap >= 6) ? gx2 : ((tap >= 3) ? gx1 : gx0);   // i = tap/3
        int jm = tap - ((tap >= 6) ? 6 : ((tap >= 3) ? 3 : 0));    // j = tap%3
        float gyj = (jm == 2) ? gy2 : ((jm == 1) ? gy1 : gy0);
        float x0f = floorf(gxi), y0f = floorf(gyj);
        float wx = gxi - x0f, wy = gyj - y0f;
        int ix0 = (int)x0f, iy0 = (int)y0f;
        int ix1 = ix0 + 1, iy1 = iy0 + 1;
        float fx0 = ((unsigned)ix0 < 64u) ? 1.f : 0.f;
        float fx1 = ((unsigned)ix1 < 64u) ? 1.f : 0.f;
        float fy0 = ((unsigned)iy0 < 64u) ? 1.f : 0.f;
        float fy1 = ((unsigned)iy1 < 64u) ? 1.f : 0.f;
        float w00 = (1.f - wy) * (1.f - wx) * fy0 * fx0;
        float w01 = (1.f - wy) * wx * fy0 * fx1;
        float w10 = wy * (1.f - wx) * fy1 * fx0;
        float w11 = wy * wx * fy1 * fx1;
        int cx0 = min(max(ix0, 0), 63), cx1 = min(max(ix1, 0), 63);
        int cy0 = min(max(iy0, 0), 63), cy1 = min(max(iy1, 0), 63);
        int r00 = ((cy0 * 64 + cx0) * CH + q8) >> 1;   // u32 index
        int r01 = ((cy0 * 64 + cx1) * CH + q8) >> 1;
        int r10 = ((cy1 * 64 + cx0) * CH + q8) >> 1;
        int r11 = ((cy1 * 64 + cx1) * CH + q8) >> 1;

        for (int q = 0; q < ncc; ++q) {
            int cc = ccb + q;
            int co = cc * 16;                     // u32 offset: 32 channels
            uint4 u00 = *(const uint4*)(xb + r00 + co);
            uint4 u01 = *(const uint4*)(xb + r01 + co);
            uint4 u10 = *(const uint4*)(xb + r10 + co);
            uint4 u11 = *(const uint4*)(xb + r11 + co);
            const u32* p00 = (const u32*)&u00;
            const u32* p01 = (const u32*)&u01;
            const u32* p10 = (const u32*)&u10;
            const u32* p11 = (const u32*)&u11;
            u32 bp[4];
            #pragma unroll
            for (int qq = 0; qq < 4; ++qq) {
                float lo = w00 * bf_lo(p00[qq]);
                lo = fmaf(w01, bf_lo(p01[qq]), lo);
                lo = fmaf(w10, bf_lo(p10[qq]), lo);
                lo = fmaf(w11, bf_lo(p11[qq]), lo);
                float hi = w00 * bf_hi(p00[qq]);
                hi = fmaf(w01, bf_hi(p01[qq]), hi);
                hi = fmaf(w10, bf_hi(p10[qq]), hi);
                hi = fmaf(w11, bf_hi(p11[qq]), hi);
                bp[qq] = pack_bf16(lo, hi);
            }
            short8 bfrag = *(const short8*)bp;
            const u16* Ap = WbSwz + ((size_t)((tap * 4 + cc) * 512 + lane) * 8);
            #pragma unroll
            for (int t = 0; t < 8; ++t) {         // t compile-time -> acc stays in VGPRs
                short8 af = *(const short8*)(Ap + (size_t)t * 512);
                acc[t] = __builtin_amdgcn_mfma_f32_16x16x32_bf16(af, bfrag, acc[t], 0, 0, 0);
            }
        }
    };

    int t0 = wave ? 5 : 0;
    for (int tt = 0; tt < 4; ++tt) process_tap(t0 + tt, 0, 4);
    process_tap(4, wave * 2, 2);                  // split tap 4 between the waves

    // ---- cross-wave reduction (wave-uniform branches, constant acc indices) ----
    if (wave == 0) {
        #pragma unroll
        for (int s = 0; s < 4; ++s) red[0][s][lane] = acc[4 + s];
    } else {
        #pragma unroll
        for (int s = 0; s < 4; ++s) red[1][s][lane] = acc[s];
    }
    __syncthreads();
    int quad4 = (lane >> 4) * 4;
    int rem = m & 4095;
    if (wave == 0) {
        #pragma unroll
        for (int s = 0; s < 4; ++s) {
            float4v v = acc[s] + red[1][s][lane];
            int ob = s * 16 + quad4;
            float4 bm = *(const float4*)(b_main + ob);
            float* op = out + (((size_t)(img * OO + ob)) << 12) + rem;
            op[0]     = v[0] + bm.x;
            op[4096]  = v[1] + bm.y;
            op[8192]  = v[2] + bm.z;
            op[12288] = v[3] + bm.w;
        }
    } else {
        #pragma unroll
        for (int s = 0; s < 4; ++s) {
            float4v v = acc[4 + s] + red[0][s][lane];
            int ob = (4 + s) * 16 + quad4;
            float4 bm = *(const float4*)(b_main + ob);
            float* op = out + (((size_t)(img * OO + ob)) << 12) + rem;
            op[0]     = v[0] + bm.x;
            op[4096]  = v[1] + bm.y;
            op[8192]  = v[2] + bm.z;
            op[12288] = v[3] + bm.w;
        }
    }
}

extern "C" void kernel_launch(void* const* d_in, const int* in_sizes, int n_in,
                              void* d_out, int out_size, void* d_ws, size_t ws_size,
                              hipStream_t stream) {
    const float* x      = (const float*)d_in[0];
    const float* w_off  = (const float*)d_in[1];
    const float* b_off  = (const float*)d_in[2];
    const float* w_main = (const float*)d_in[3];
    const float* b_main = (const float*)d_in[4];
    float* out = (float*)d_out;

    char* ws = (char*)d_ws;
    __hip_bfloat16* xt = (__hip_bfloat16*)ws;                         // 8 MB
    float* partial = (float*)(ws + 8388608);                          // 3 MB
    u16* WbSwz = (u16*)(ws + 8388608 + 3145728);                      // 288 KB

    prep_kernel<<<1096, 256, 0, stream>>>(x, w_off, w_main, xt, partial, WbSwz);
    fused_gemm_kernel<<<2048, 128, 0, stream>>>(xt, partial, b_off, WbSwz, b_main, out);
}